// Round 8
// baseline (2106.874 us; speedup 1.0000x reference)
//
#include <hip/hip_runtime.h>
#include <stdint.h>

// B=1024, T=187, H=256, C=5. Fully-fused persistent 2-layer RNN + FC.
// Transposed recurrence: ht = h^T in LDS as [batch col][feature]; state is
// the MFMA B-operand, weights (A-operand f16 frags) arch-register-resident
// with overflow SPILLED TO SCRATCH (deliberate: L2-resident, loop-invariant
// addresses -> scheduler prefetches them well; measured best).
// 64 blocks x 16 batch cols, 8 waves, 32-feature M-slice/wave.
//
// Measured history: R8 all-in-regs+spill~150 = 318us (best). Original
// w1lds = 347.8us (LDS weight reads sit on layer1 dep chain - worse than
// scratch stream). R11 AGPR pins = 431us. R12 pins+w1lds = NaN (miscompile).
// AGPR-pin family abandoned (0-for-2).
// Key arithmetic: weights = 384KB/CU vs 256KB arch half at 2 waves/SIMD ->
// >=128KB/step must stream regardless; kernel is weight-streaming-bound.
// R13 (this round): shrink non-weight arch demand so more weights stay
// resident: (a) #pragma unroll 2 on kt loops caps B-frags in flight
// (~32->~10 regs); (b) biases/wi0 -> LDS (in-loop __syncthreads is an LDS
// memory barrier -> compiler can't hoist them back to regs), accs init
// with zero C-in, bias added at tanh (identical f32 math). Demand
// 284->~246, spill ~156->~118, streamed 307->242KB/step.
// Falsifiable: WRITE_SIZE 25.6 -> ~18-20MB, dur 318 -> 260-290us.
// Gate: dur >= 310 => spill lever exhausted, pivot to 32-col amortization.

#define Bsz 1024
#define Tt  187
#define Hh  256
#define Cc  5
#define ST  264      // f16 elems per batch-col row (256 + 8 pad)
#define XS  188      // x LDS stride (187 + 1)

typedef _Float16 f16x8 __attribute__((ext_vector_type(8)));
typedef __fp16   fp16x2 __attribute__((ext_vector_type(2)));  // cvt_pkrtz native type
typedef float    f32x4 __attribute__((ext_vector_type(4)));

__device__ __forceinline__ float tanh_fast(float z) {
    float e = __expf(2.0f * z);
    return 1.0f - 2.0f * __builtin_amdgcn_rcpf(1.0f + e);
}

__device__ __forceinline__ unsigned pk2(float a, float b) {
    union { fp16x2 h; unsigned u; } v;
    v.h = __builtin_amdgcn_cvt_pkrtz(a, b);
    return v.u;
}

__global__ void __launch_bounds__(512, 2)
rnn_fused(const float* __restrict__ x,     // [B][T]
          const float* __restrict__ Wih0,  // [H][1]
          const float* __restrict__ Whh0,  // [H][H]
          const float* __restrict__ bih0,
          const float* __restrict__ bhh0,
          const float* __restrict__ Wih1,  // [H][H]
          const float* __restrict__ Whh1,  // [H][H]
          const float* __restrict__ bih1,
          const float* __restrict__ bhh1,
          const float* __restrict__ Wfc,   // [C][H]
          const float* __restrict__ bfc,   // [C]
          float* __restrict__ out)         // [B][C]
{
    __shared__ __align__(16) _Float16 ht0[2][16 * ST];
    __shared__ __align__(16) _Float16 ht1[2][16 * ST];
    __shared__ float xs[16 * XS];
    __shared__ __align__(16) float bias_lds[3 * Hh];  // [0]=b0sum [1]=b1sum [2]=wi0

    const int tid  = threadIdx.x;
    const int lane = tid & 63;
    const int w    = tid >> 6;     // wave 0..7 -> features [32w, 32w+32)
    const int q    = lane >> 4;
    const int c    = lane & 15;    // batch col within block
    const int bb   = blockIdx.x * 16;

    // ---- one-time: stage weight A-fragments (f16), all three matrices ----
    // A-layout: lane (q,c) reg j holds A[m=c][k=kt*32+q*8+j].
    // Overflow beyond the 128-reg arch half spills to scratch (intended).
    f16x8 wh0[2][8], wi1[2][8], wh1[2][8];
#pragma unroll
    for (int mt = 0; mt < 2; ++mt) {
        const int fb = 32 * w + 16 * mt;
        const int m = fb + c;
#pragma unroll
        for (int kt = 0; kt < 8; ++kt) {
            const int off = m * Hh + kt * 32 + q * 8;
            {
                const float4 a0 = *(const float4*)(Whh0 + off);
                const float4 a1 = *(const float4*)(Whh0 + off + 4);
                wh0[mt][kt] = (f16x8){(_Float16)a0.x, (_Float16)a0.y, (_Float16)a0.z, (_Float16)a0.w,
                                      (_Float16)a1.x, (_Float16)a1.y, (_Float16)a1.z, (_Float16)a1.w};
            }
            {
                const float4 a0 = *(const float4*)(Wih1 + off);
                const float4 a1 = *(const float4*)(Wih1 + off + 4);
                wi1[mt][kt] = (f16x8){(_Float16)a0.x, (_Float16)a0.y, (_Float16)a0.z, (_Float16)a0.w,
                                      (_Float16)a1.x, (_Float16)a1.y, (_Float16)a1.z, (_Float16)a1.w};
            }
            {
                const float4 a0 = *(const float4*)(Whh1 + off);
                const float4 a1 = *(const float4*)(Whh1 + off + 4);
                wh1[mt][kt] = (f16x8){(_Float16)a0.x, (_Float16)a0.y, (_Float16)a0.z, (_Float16)a0.w,
                                      (_Float16)a1.x, (_Float16)a1.y, (_Float16)a1.z, (_Float16)a1.w};
            }
        }
    }

    // ---- init LDS: x tile, biases, ht1 = 0 (both buffers), ht0[0] ----
    for (int i = tid; i < 16 * Tt; i += 512) {
        const int b = i / Tt, t = i - b * Tt;
        xs[b * XS + t] = x[(bb + b) * Tt + t];
    }
    if (tid < Hh) {
        bias_lds[tid]           = bih0[tid] + bhh0[tid];
        bias_lds[Hh + tid]      = bih1[tid] + bhh1[tid];
        bias_lds[2 * Hh + tid]  = Wih0[tid];
    }
    {
        _Float16* z = &ht1[0][0];
        for (int i = tid; i < 2 * 16 * ST; i += 512) z[i] = (_Float16)0.f;
    }
    for (int i = tid; i < 16 * Hh; i += 512) {
        const int b = i >> 8, f = i & 255;
        const float xv0 = x[(bb + b) * Tt];
        ht0[0][b * ST + f] =
            (_Float16)tanh_fast(xv0 * Wih0[f] + bih0[f] + bhh0[f]);
    }
    __syncthreads();

    // B-operand read base: lane (q,c) reg j needs ht[k=kt*32+q*8+j][col c]
    const int rdoff = c * ST + q * 8;
    const int wroff = c * ST + 32 * w + 4 * q;   // D write: [c][fb+4q .. +3]
    const int fq    = 32 * w + 4 * q;            // bias base for mt=0 (add 16 for mt=1)

    // ---- main recurrence, time-skewed:
    // step s: B0 = ht0[s]; produce ht0[s+1] (Whh0) and ht1[s] (Wih1 + Whh1)
#pragma unroll 1
    for (int s = 0; s < Tt; ++s) {
        const int cur = s & 1, nxt = cur ^ 1;
        const _Float16* B0p = &ht0[cur][rdoff];
        const _Float16* B1p = &ht1[nxt][rdoff];   // ht1[s-1]
        int sn = s + 1; if (sn >= Tt) sn = Tt - 1;  // last h0_next unused
        const float xv = xs[c * XS + sn];

        // layer0: ai = Wih1 . ht0 ; ah0 = Whh0 . ht0 (shared B-frag).
        // Zero C-in; biases added at tanh time (identical f32 adds).
        const f32x4 z4 = (f32x4){0.f, 0.f, 0.f, 0.f};
        f32x4 ai[2]  = {z4, z4};
        f32x4 ah0[2] = {z4, z4};
#pragma unroll 2
        for (int kt = 0; kt < 8; ++kt) {
            const f16x8 B = *(const f16x8*)(B0p + kt * 32);
            ai[0]  = __builtin_amdgcn_mfma_f32_16x16x32_f16(wi1[0][kt], B, ai[0],  0, 0, 0);
            ai[1]  = __builtin_amdgcn_mfma_f32_16x16x32_f16(wi1[1][kt], B, ai[1],  0, 0, 0);
            ah0[0] = __builtin_amdgcn_mfma_f32_16x16x32_f16(wh0[0][kt], B, ah0[0], 0, 0, 0);
            ah0[1] = __builtin_amdgcn_mfma_f32_16x16x32_f16(wh0[1][kt], B, ah0[1], 0, 0, 0);
        }
        // ht0[s+1] = tanh(ah0 + b0 + x_{s+1} * wi0), pack f16, 8B LDS writes
#pragma unroll
        for (int mt = 0; mt < 2; ++mt) {
            const float4 b0r = *(const float4*)&bias_lds[fq + 16 * mt];
            const float4 w0r = *(const float4*)&bias_lds[2 * Hh + fq + 16 * mt];
            const float t0 = tanh_fast(ah0[mt][0] + b0r.x + xv * w0r.x);
            const float t1 = tanh_fast(ah0[mt][1] + b0r.y + xv * w0r.y);
            const float t2 = tanh_fast(ah0[mt][2] + b0r.z + xv * w0r.z);
            const float t3 = tanh_fast(ah0[mt][3] + b0r.w + xv * w0r.w);
            *(uint2*)(&ht0[nxt][wroff + 16 * mt]) = make_uint2(pk2(t0, t1), pk2(t2, t3));
        }

        // layer1: ah1 = Whh1 . ht1[s-1]
        f32x4 ah1[2] = {z4, z4};
#pragma unroll 2
        for (int kt = 0; kt < 8; ++kt) {
            const f16x8 B = *(const f16x8*)(B1p + kt * 32);
            ah1[0] = __builtin_amdgcn_mfma_f32_16x16x32_f16(wh1[0][kt], B, ah1[0], 0, 0, 0);
            ah1[1] = __builtin_amdgcn_mfma_f32_16x16x32_f16(wh1[1][kt], B, ah1[1], 0, 0, 0);
        }
        // ht1[s] = tanh(ai + ah1 + b1)
#pragma unroll
        for (int mt = 0; mt < 2; ++mt) {
            const float4 b1r = *(const float4*)&bias_lds[Hh + fq + 16 * mt];
            const float t0 = tanh_fast(ai[mt][0] + ah1[mt][0] + b1r.x);
            const float t1 = tanh_fast(ai[mt][1] + ah1[mt][1] + b1r.y);
            const float t2 = tanh_fast(ai[mt][2] + ah1[mt][2] + b1r.z);
            const float t3 = tanh_fast(ai[mt][3] + ah1[mt][3] + b1r.w);
            *(uint2*)(&ht1[cur][wroff + 16 * mt]) = make_uint2(pk2(t0, t1), pk2(t2, t3));
        }
        __syncthreads();   // double-buffered: one barrier per step
    }

    // ---- FC epilogue: out[bb+b][cls] = ht1_final[.][b] . Wfc[cls] + bfc ----
    if (tid < 16 * Cc) {
        const int b = tid / Cc, cls = tid - Cc * (tid / Cc);
        const _Float16* h = &ht1[(Tt - 1) & 1][b * ST];
        float acc = bfc[cls];
        for (int k = 0; k < Hh; ++k)
            acc += (float)h[k] * Wfc[cls * Hh + k];
        out[(bb + b) * Cc + cls] = acc;
    }
}

extern "C" void kernel_launch(void* const* d_in, const int* in_sizes, int n_in,
                              void* d_out, int out_size, void* d_ws, size_t ws_size,
                              hipStream_t stream) {
    rnn_fused<<<dim3(Bsz / 16), dim3(512), 0, stream>>>(
        (const float*)d_in[0],  // x
        (const float*)d_in[1],  // W_ih0
        (const float*)d_in[2],  // W_hh0
        (const float*)d_in[3],  // b_ih0
        (const float*)d_in[4],  // b_hh0
        (const float*)d_in[5],  // W_ih1
        (const float*)d_in[6],  // W_hh1
        (const float*)d_in[7],  // b_ih1
        (const float*)d_in[8],  // b_hh1
        (const float*)d_in[9],  // W_fc
        (const float*)d_in[10], // b_fc
        (float*)d_out);
}

// Round 9
// 568.104 us; speedup vs baseline: 3.7086x; 3.7086x over previous
//
#include <hip/hip_runtime.h>
#include <stdint.h>

// B=1024, T=187, H=256, C=5. Fully-fused persistent 2-layer RNN + FC.
// Transposed recurrence: ht = h^T in LDS as [batch col][feature]; state is
// the MFMA B-operand, weights (A-operand f16 frags) register-resident.
//
// R14 REDESIGN (after R13's unroll-2 disaster, VGPR=44, all-scratch, 2107us):
// The session-long bottleneck is the per-wave register budget: at 8 waves/
// block the allocator targets 4 waves/SIMD -> 128 regs -> ~195 scratch
// slots re-streamed every step (R8 = 318us best). No attribute spelling
// changed it. So change the GEOMETRY instead:
//   256-thread block, __launch_bounds__(256,1) -> 4 waves/CU = 1 wave/SIMD
//   -> 512-reg unified budget per wave (m97 precedent: arch >128 is real).
//   4 waves x 64 features (mt=4). Weights/wave = 3*4*8*4 = 384 regs
//   + acc 32 + f16-packed bias 24 + B/misc ~40 = ~480 <= 512: NO SPILL.
// Side benefits: MFMA per B-read doubles (8 vs 4) -> LDS B-traffic halves
// (64KB/step/CU); serial chain fully register-resident.
// FALSIFIABLE: VGPR_Count must read >256 (expect ~450-500) and WRITE_SIZE
// 25.6MB -> <1MB. If VGPR_Count==128 again, 512-budget is refuted ->
// all future designs must fit 128.
// Full #pragma unroll everywhere (R13 lesson: partial unroll -> runtime
// index -> arrays demoted to scratch).

#define Bsz 1024
#define Tt  187
#define Hh  256
#define Cc  5
#define ST  264      // f16 elems per batch-col row (256 + 8 pad)
#define XS  188      // x LDS stride (187 + 1)

typedef _Float16 f16x8 __attribute__((ext_vector_type(8)));
typedef _Float16 f16x4 __attribute__((ext_vector_type(4)));
typedef __fp16   fp16x2 __attribute__((ext_vector_type(2)));  // cvt_pkrtz native type
typedef float    f32x4 __attribute__((ext_vector_type(4)));

__device__ __forceinline__ float tanh_fast(float z) {
    float e = __expf(2.0f * z);
    return 1.0f - 2.0f * __builtin_amdgcn_rcpf(1.0f + e);
}

__device__ __forceinline__ unsigned pk2(float a, float b) {
    union { fp16x2 h; unsigned u; } v;
    v.h = __builtin_amdgcn_cvt_pkrtz(a, b);
    return v.u;
}

__global__ void __launch_bounds__(256, 1)
rnn_fused(const float* __restrict__ x,     // [B][T]
          const float* __restrict__ Wih0,  // [H][1]
          const float* __restrict__ Whh0,  // [H][H]
          const float* __restrict__ bih0,
          const float* __restrict__ bhh0,
          const float* __restrict__ Wih1,  // [H][H]
          const float* __restrict__ Whh1,  // [H][H]
          const float* __restrict__ bih1,
          const float* __restrict__ bhh1,
          const float* __restrict__ Wfc,   // [C][H]
          const float* __restrict__ bfc,   // [C]
          float* __restrict__ out)         // [B][C]
{
    __shared__ __align__(16) _Float16 ht0[2][16 * ST];
    __shared__ __align__(16) _Float16 ht1[2][16 * ST];
    __shared__ float xs[16 * XS];

    const int tid  = threadIdx.x;
    const int lane = tid & 63;
    const int w    = tid >> 6;     // wave 0..3 -> features [64w, 64w+64)
    const int q    = lane >> 4;
    const int c    = lane & 15;    // batch col within block
    const int bb   = blockIdx.x * 16;

    // ---- one-time: stage weight A-fragments (f16), all three matrices ----
    // A-layout: lane (q,c) reg j holds A[m][k=kt*32+q*8+j], m = fb+c,
    // fb = 64*w + 16*mt, mt in 0..3.
    f16x8 wh0[4][8], wi1[4][8], wh1[4][8];       // 384 regs
    f16x4 b0h[4], b1h[4], wi0h[4];               // f16-packed per-feature consts
#pragma unroll
    for (int mt = 0; mt < 4; ++mt) {
        const int fb = 64 * w + 16 * mt;
#pragma unroll
        for (int r = 0; r < 4; ++r) {
            const int f = fb + 4 * q + r;
            b0h[mt][r]  = (_Float16)(bih0[f] + bhh0[f]);
            b1h[mt][r]  = (_Float16)(bih1[f] + bhh1[f]);
            wi0h[mt][r] = (_Float16)(Wih0[f]);
        }
        const int m = fb + c;
#pragma unroll
        for (int kt = 0; kt < 8; ++kt) {
            const int off = m * Hh + kt * 32 + q * 8;
            {
                const float4 a0 = *(const float4*)(Whh0 + off);
                const float4 a1 = *(const float4*)(Whh0 + off + 4);
                wh0[mt][kt] = (f16x8){(_Float16)a0.x, (_Float16)a0.y, (_Float16)a0.z, (_Float16)a0.w,
                                      (_Float16)a1.x, (_Float16)a1.y, (_Float16)a1.z, (_Float16)a1.w};
            }
            {
                const float4 a0 = *(const float4*)(Wih1 + off);
                const float4 a1 = *(const float4*)(Wih1 + off + 4);
                wi1[mt][kt] = (f16x8){(_Float16)a0.x, (_Float16)a0.y, (_Float16)a0.z, (_Float16)a0.w,
                                      (_Float16)a1.x, (_Float16)a1.y, (_Float16)a1.z, (_Float16)a1.w};
            }
            {
                const float4 a0 = *(const float4*)(Whh1 + off);
                const float4 a1 = *(const float4*)(Whh1 + off + 4);
                wh1[mt][kt] = (f16x8){(_Float16)a0.x, (_Float16)a0.y, (_Float16)a0.z, (_Float16)a0.w,
                                      (_Float16)a1.x, (_Float16)a1.y, (_Float16)a1.z, (_Float16)a1.w};
            }
        }
    }

    // ---- init LDS: x tile, ht1 = 0 (both buffers), ht0[0] = state t=0 ----
    for (int i = tid; i < 16 * Tt; i += 256) {
        const int b = i / Tt, t = i - b * Tt;
        xs[b * XS + t] = x[(bb + b) * Tt + t];
    }
    {
        _Float16* z = &ht1[0][0];
        for (int i = tid; i < 2 * 16 * ST; i += 256) z[i] = (_Float16)0.f;
    }
    for (int i = tid; i < 16 * Hh; i += 256) {
        const int b = i >> 8, f = i & 255;
        const float xv0 = x[(bb + b) * Tt];
        ht0[0][b * ST + f] =
            (_Float16)tanh_fast(xv0 * Wih0[f] + bih0[f] + bhh0[f]);
    }
    __syncthreads();

    // B-operand read base: lane (q,c) reg j needs ht[k=kt*32+q*8+j][col c]
    const int rdoff = c * ST + q * 8;
    const int wroff = c * ST + 64 * w + 4 * q;   // D write: [c][fb+4q .. +3]

    // ---- main recurrence, time-skewed:
    // step s: B0 = ht0[s]; produce ht0[s+1] (Whh0) and ht1[s] (Wih1 + Whh1)
#pragma unroll 1
    for (int s = 0; s < Tt; ++s) {
        const int cur = s & 1, nxt = cur ^ 1;
        const _Float16* B0p = &ht0[cur][rdoff];
        const _Float16* B1p = &ht1[nxt][rdoff];   // ht1[s-1]
        int sn = s + 1; if (sn >= Tt) sn = Tt - 1;  // last h0_next unused
        const float xv = xs[c * XS + sn];

        // layer0: ai = Wih1 . ht0 ; ah0 = Whh0 . ht0 (shared B-frag).
        // Zero C-in; biases added at tanh (identical f32 adds).
        const f32x4 z4 = (f32x4){0.f, 0.f, 0.f, 0.f};
        f32x4 ai[4]  = {z4, z4, z4, z4};
        f32x4 ah0[4] = {z4, z4, z4, z4};
#pragma unroll
        for (int kt = 0; kt < 8; ++kt) {
            const f16x8 B = *(const f16x8*)(B0p + kt * 32);
#pragma unroll
            for (int mt = 0; mt < 4; ++mt) {
                ai[mt]  = __builtin_amdgcn_mfma_f32_16x16x32_f16(wi1[mt][kt], B, ai[mt],  0, 0, 0);
                ah0[mt] = __builtin_amdgcn_mfma_f32_16x16x32_f16(wh0[mt][kt], B, ah0[mt], 0, 0, 0);
            }
        }
        // ht0[s+1] = tanh(ah0 + b0 + x_{s+1} * wi0), pack f16, 8B LDS writes
#pragma unroll
        for (int mt = 0; mt < 4; ++mt) {
            const float t0 = tanh_fast(ah0[mt][0] + (float)b0h[mt][0] + xv * (float)wi0h[mt][0]);
            const float t1 = tanh_fast(ah0[mt][1] + (float)b0h[mt][1] + xv * (float)wi0h[mt][1]);
            const float t2 = tanh_fast(ah0[mt][2] + (float)b0h[mt][2] + xv * (float)wi0h[mt][2]);
            const float t3 = tanh_fast(ah0[mt][3] + (float)b0h[mt][3] + xv * (float)wi0h[mt][3]);
            *(uint2*)(&ht0[nxt][wroff + 16 * mt]) = make_uint2(pk2(t0, t1), pk2(t2, t3));
        }

        // layer1: ah1 = Whh1 . ht1[s-1]
        f32x4 ah1[4] = {z4, z4, z4, z4};
#pragma unroll
        for (int kt = 0; kt < 8; ++kt) {
            const f16x8 B = *(const f16x8*)(B1p + kt * 32);
#pragma unroll
            for (int mt = 0; mt < 4; ++mt) {
                ah1[mt] = __builtin_amdgcn_mfma_f32_16x16x32_f16(wh1[mt][kt], B, ah1[mt], 0, 0, 0);
            }
        }
        // ht1[s] = tanh(ai + ah1 + b1)
#pragma unroll
        for (int mt = 0; mt < 4; ++mt) {
            const float t0 = tanh_fast(ai[mt][0] + ah1[mt][0] + (float)b1h[mt][0]);
            const float t1 = tanh_fast(ai[mt][1] + ah1[mt][1] + (float)b1h[mt][1]);
            const float t2 = tanh_fast(ai[mt][2] + ah1[mt][2] + (float)b1h[mt][2]);
            const float t3 = tanh_fast(ai[mt][3] + ah1[mt][3] + (float)b1h[mt][3]);
            *(uint2*)(&ht1[cur][wroff + 16 * mt]) = make_uint2(pk2(t0, t1), pk2(t2, t3));
        }
        __syncthreads();   // double-buffered: one barrier per step
    }

    // ---- FC epilogue: out[bb+b][cls] = ht1_final[.][b] . Wfc[cls] + bfc ----
    if (tid < 16 * Cc) {
        const int b = tid / Cc, cls = tid - Cc * (tid / Cc);
        const _Float16* h = &ht1[(Tt - 1) & 1][b * ST];
        float acc = bfc[cls];
        for (int k = 0; k < Hh; ++k)
            acc += (float)h[k] * Wfc[cls * Hh + k];
        out[(bb + b) * Cc + cls] = acc;
    }
}

extern "C" void kernel_launch(void* const* d_in, const int* in_sizes, int n_in,
                              void* d_out, int out_size, void* d_ws, size_t ws_size,
                              hipStream_t stream) {
    rnn_fused<<<dim3(Bsz / 16), dim3(256), 0, stream>>>(
        (const float*)d_in[0],  // x
        (const float*)d_in[1],  // W_ih0
        (const float*)d_in[2],  // W_hh0
        (const float*)d_in[3],  // b_ih0
        (const float*)d_in[4],  // b_hh0
        (const float*)d_in[5],  // W_ih1
        (const float*)d_in[6],  // W_hh1
        (const float*)d_in[7],  // b_ih1
        (const float*)d_in[8],  // b_hh1
        (const float*)d_in[9],  // W_fc
        (const float*)d_in[10], // b_fc
        (float*)d_out);
}

// Round 10
// 482.809 us; speedup vs baseline: 4.3638x; 1.1767x over previous
//
#include <hip/hip_runtime.h>
#include <stdint.h>

// B=1024, T=187, H=256, C=5. Fully-fused persistent 2-layer RNN + FC.
// Transposed recurrence: ht = h^T in LDS as [batch col][feature]; state is
// the MFMA B-operand, weights (A-operand f16 frags) register-resident.
//
// REGISTER MODEL (established R8+R14, measured):
//   pool = 2048 unified regs/SIMD; regs/wave = 2048 / waves-per-SIMD.
//   arch VGPRs cap at 256 (ISA encoding v0..v255); remainder is AGPR-only.
//   R8  (2 w/SIMD): 256/wave = 128 arch + 128 agpr -> ~150 spilled, 318us.
//   R14 (1 w/SIMD): 512/wave = 256 arch + 256 agpr; compiler does NOT
//       spill into idle AGPRs -> ~224 slots to scratch, WRITE 37MB, and
//       with 1 wave/SIMD no TLP hides reloads -> 528us.
// R15 (this round): claim the AGPR half explicitly. Pin wi1+wh1 (256 regs,
//   exactly the AGPR half) via asm "+a" -- the SAME pin pair R11 proved
//   correct. MFMA A-operands read AGPRs natively (ISA sec 10), no copies.
//   Arch half: wh0 128 + acc <=48 + bias 24 + B-frags <=32 + misc ~12
//   ~= 244 <= 256. Zero structural spill.
// FALSIFIABLE: WRITE_SIZE 37.3MB -> <2MB; dur -> 100-170us (kill branch
// if >= 318 = R8). VGPR_Count staying 256 is EXPECTED (arch half full).
// Full #pragma unroll everywhere (R13 lesson: partial unroll -> runtime
// index -> arrays demoted to scratch, 2107us).

#define Bsz 1024
#define Tt  187
#define Hh  256
#define Cc  5
#define ST  264      // f16 elems per batch-col row (256 + 8 pad)
#define XS  188      // x LDS stride (187 + 1)

typedef _Float16 f16x8 __attribute__((ext_vector_type(8)));
typedef _Float16 f16x4 __attribute__((ext_vector_type(4)));
typedef __fp16   fp16x2 __attribute__((ext_vector_type(2)));  // cvt_pkrtz native type
typedef float    f32x4 __attribute__((ext_vector_type(4)));

// Force a fragment to live in the AGPR half of the unified file (R11-proven).
#define PIN_AGPR(v) asm volatile("" : "+a"(v))

__device__ __forceinline__ float tanh_fast(float z) {
    float e = __expf(2.0f * z);
    return 1.0f - 2.0f * __builtin_amdgcn_rcpf(1.0f + e);
}

__device__ __forceinline__ unsigned pk2(float a, float b) {
    union { fp16x2 h; unsigned u; } v;
    v.h = __builtin_amdgcn_cvt_pkrtz(a, b);
    return v.u;
}

__global__ void __launch_bounds__(256, 1)
rnn_fused(const float* __restrict__ x,     // [B][T]
          const float* __restrict__ Wih0,  // [H][1]
          const float* __restrict__ Whh0,  // [H][H]
          const float* __restrict__ bih0,
          const float* __restrict__ bhh0,
          const float* __restrict__ Wih1,  // [H][H]
          const float* __restrict__ Whh1,  // [H][H]
          const float* __restrict__ bih1,
          const float* __restrict__ bhh1,
          const float* __restrict__ Wfc,   // [C][H]
          const float* __restrict__ bfc,   // [C]
          float* __restrict__ out)         // [B][C]
{
    __shared__ __align__(16) _Float16 ht0[2][16 * ST];
    __shared__ __align__(16) _Float16 ht1[2][16 * ST];
    __shared__ float xs[16 * XS];

    const int tid  = threadIdx.x;
    const int lane = tid & 63;
    const int w    = tid >> 6;     // wave 0..3 -> features [64w, 64w+64)
    const int q    = lane >> 4;
    const int c    = lane & 15;    // batch col within block
    const int bb   = blockIdx.x * 16;

    // ---- one-time: stage weight A-fragments (f16), all three matrices ----
    // A-layout: lane (q,c) reg j holds A[m][k=kt*32+q*8+j], m = fb+c,
    // fb = 64*w + 16*mt, mt in 0..3.
    // wi1, wh1 -> AGPR half (pinned, 256 exactly). wh0 -> arch VGPRs.
    f16x8 wh0[4][8], wi1[4][8], wh1[4][8];       // 384 regs total
    f16x4 b0h[4], b1h[4], wi0h[4];               // f16-packed per-feature consts
#pragma unroll
    for (int mt = 0; mt < 4; ++mt) {
        const int fb = 64 * w + 16 * mt;
#pragma unroll
        for (int r = 0; r < 4; ++r) {
            const int f = fb + 4 * q + r;
            b0h[mt][r]  = (_Float16)(bih0[f] + bhh0[f]);
            b1h[mt][r]  = (_Float16)(bih1[f] + bhh1[f]);
            wi0h[mt][r] = (_Float16)(Wih0[f]);
        }
        const int m = fb + c;
#pragma unroll
        for (int kt = 0; kt < 8; ++kt) {
            const int off = m * Hh + kt * 32 + q * 8;
            {
                const float4 a0 = *(const float4*)(Whh0 + off);
                const float4 a1 = *(const float4*)(Whh0 + off + 4);
                wh0[mt][kt] = (f16x8){(_Float16)a0.x, (_Float16)a0.y, (_Float16)a0.z, (_Float16)a0.w,
                                      (_Float16)a1.x, (_Float16)a1.y, (_Float16)a1.z, (_Float16)a1.w};
            }
            {
                const float4 a0 = *(const float4*)(Wih1 + off);
                const float4 a1 = *(const float4*)(Wih1 + off + 4);
                wi1[mt][kt] = (f16x8){(_Float16)a0.x, (_Float16)a0.y, (_Float16)a0.z, (_Float16)a0.w,
                                      (_Float16)a1.x, (_Float16)a1.y, (_Float16)a1.z, (_Float16)a1.w};
                PIN_AGPR(wi1[mt][kt]);
            }
            {
                const float4 a0 = *(const float4*)(Whh1 + off);
                const float4 a1 = *(const float4*)(Whh1 + off + 4);
                wh1[mt][kt] = (f16x8){(_Float16)a0.x, (_Float16)a0.y, (_Float16)a0.z, (_Float16)a0.w,
                                      (_Float16)a1.x, (_Float16)a1.y, (_Float16)a1.z, (_Float16)a1.w};
                PIN_AGPR(wh1[mt][kt]);
            }
        }
    }

    // ---- init LDS: x tile, ht1 = 0 (both buffers), ht0[0] = state t=0 ----
    for (int i = tid; i < 16 * Tt; i += 256) {
        const int b = i / Tt, t = i - b * Tt;
        xs[b * XS + t] = x[(bb + b) * Tt + t];
    }
    {
        _Float16* z = &ht1[0][0];
        for (int i = tid; i < 2 * 16 * ST; i += 256) z[i] = (_Float16)0.f;
    }
    for (int i = tid; i < 16 * Hh; i += 256) {
        const int b = i >> 8, f = i & 255;
        const float xv0 = x[(bb + b) * Tt];
        ht0[0][b * ST + f] =
            (_Float16)tanh_fast(xv0 * Wih0[f] + bih0[f] + bhh0[f]);
    }
    __syncthreads();

    // B-operand read base: lane (q,c) reg j needs ht[k=kt*32+q*8+j][col c]
    const int rdoff = c * ST + q * 8;
    const int wroff = c * ST + 64 * w + 4 * q;   // D write: [c][fb+4q .. +3]

    // ---- main recurrence, time-skewed:
    // step s: B0 = ht0[s]; produce ht0[s+1] (Whh0) and ht1[s] (Wih1 + Whh1)
#pragma unroll 1
    for (int s = 0; s < Tt; ++s) {
        const int cur = s & 1, nxt = cur ^ 1;
        const _Float16* B0p = &ht0[cur][rdoff];
        const _Float16* B1p = &ht1[nxt][rdoff];   // ht1[s-1]
        int sn = s + 1; if (sn >= Tt) sn = Tt - 1;  // last h0_next unused
        const float xv = xs[c * XS + sn];

        // layer0: ai = Wih1 . ht0 ; ah0 = Whh0 . ht0 (shared B-frag).
        // Zero C-in; biases added at tanh (identical f32 adds).
        const f32x4 z4 = (f32x4){0.f, 0.f, 0.f, 0.f};
        f32x4 ai[4]  = {z4, z4, z4, z4};
        f32x4 ah0[4] = {z4, z4, z4, z4};
#pragma unroll
        for (int kt = 0; kt < 8; ++kt) {
            const f16x8 B = *(const f16x8*)(B0p + kt * 32);
#pragma unroll
            for (int mt = 0; mt < 4; ++mt) {
                ai[mt]  = __builtin_amdgcn_mfma_f32_16x16x32_f16(wi1[mt][kt], B, ai[mt],  0, 0, 0);
                ah0[mt] = __builtin_amdgcn_mfma_f32_16x16x32_f16(wh0[mt][kt], B, ah0[mt], 0, 0, 0);
            }
        }
        // ht0[s+1] = tanh(ah0 + b0 + x_{s+1} * wi0), pack f16, 8B LDS writes
#pragma unroll
        for (int mt = 0; mt < 4; ++mt) {
            const float t0 = tanh_fast(ah0[mt][0] + (float)b0h[mt][0] + xv * (float)wi0h[mt][0]);
            const float t1 = tanh_fast(ah0[mt][1] + (float)b0h[mt][1] + xv * (float)wi0h[mt][1]);
            const float t2 = tanh_fast(ah0[mt][2] + (float)b0h[mt][2] + xv * (float)wi0h[mt][2]);
            const float t3 = tanh_fast(ah0[mt][3] + (float)b0h[mt][3] + xv * (float)wi0h[mt][3]);
            *(uint2*)(&ht0[nxt][wroff + 16 * mt]) = make_uint2(pk2(t0, t1), pk2(t2, t3));
        }

        // layer1: ah1 = Whh1 . ht1[s-1]; weights AGPR-resident
        f32x4 ah1[4] = {z4, z4, z4, z4};
#pragma unroll
        for (int kt = 0; kt < 8; ++kt) {
            const f16x8 B = *(const f16x8*)(B1p + kt * 32);
#pragma unroll
            for (int mt = 0; mt < 4; ++mt) {
                ah1[mt] = __builtin_amdgcn_mfma_f32_16x16x32_f16(wh1[mt][kt], B, ah1[mt], 0, 0, 0);
            }
        }
        // ht1[s] = tanh(ai + ah1 + b1)
#pragma unroll
        for (int mt = 0; mt < 4; ++mt) {
            const float t0 = tanh_fast(ai[mt][0] + ah1[mt][0] + (float)b1h[mt][0]);
            const float t1 = tanh_fast(ai[mt][1] + ah1[mt][1] + (float)b1h[mt][1]);
            const float t2 = tanh_fast(ai[mt][2] + ah1[mt][2] + (float)b1h[mt][2]);
            const float t3 = tanh_fast(ai[mt][3] + ah1[mt][3] + (float)b1h[mt][3]);
            *(uint2*)(&ht1[cur][wroff + 16 * mt]) = make_uint2(pk2(t0, t1), pk2(t2, t3));
        }
        __syncthreads();   // double-buffered: one barrier per step
    }

    // ---- FC epilogue: out[bb+b][cls] = ht1_final[.][b] . Wfc[cls] + bfc ----
    if (tid < 16 * Cc) {
        const int b = tid / Cc, cls = tid - Cc * (tid / Cc);
        const _Float16* h = &ht1[(Tt - 1) & 1][b * ST];
        float acc = bfc[cls];
        for (int k = 0; k < Hh; ++k)
            acc += (float)h[k] * Wfc[cls * Hh + k];
        out[(bb + b) * Cc + cls] = acc;
    }
}

extern "C" void kernel_launch(void* const* d_in, const int* in_sizes, int n_in,
                              void* d_out, int out_size, void* d_ws, size_t ws_size,
                              hipStream_t stream) {
    rnn_fused<<<dim3(Bsz / 16), dim3(256), 0, stream>>>(
        (const float*)d_in[0],  // x
        (const float*)d_in[1],  // W_ih0
        (const float*)d_in[2],  // W_hh0
        (const float*)d_in[3],  // b_ih0
        (const float*)d_in[4],  // b_hh0
        (const float*)d_in[5],  // W_ih1
        (const float*)d_in[6],  // W_hh1
        (const float*)d_in[7],  // b_ih1
        (const float*)d_in[8],  // b_hh1
        (const float*)d_in[9],  // W_fc
        (const float*)d_in[10], // b_fc
        (float*)d_out);
}

// Round 11
// 368.363 us; speedup vs baseline: 5.7196x; 1.3107x over previous
//
#include <hip/hip_runtime.h>
#include <stdint.h>

// B=1024, T=187, H=256, C=5. Fully-fused persistent 2-layer RNN + FC.
// Transposed recurrence: ht = h^T in LDS as [batch col][feature]; state is
// the MFMA B-operand, weights (A-operand f16 frags) register-resident.
// 64 blocks x 16 batch cols, 8 waves, 32-feature M-slice/wave.
//
// REGISTER MODEL (measured, R8/R11/R14/R15):
//   pool = 512 unified regs/SIMD; regs/wave = 512 / waves-per-SIMD;
//   arch VGPRs cap at half (128 at 2 w/SIMD); compiler NEVER spills into
//   idle AGPRs; asm "+a" pins work (R11/R15: WRITE_SIZE collapsed);
//   TLP >= 2 waves/SIMD is worth more than 2x budget (R15: 1 w/SIMD =
//   425us despite 512 regs -> killed by gate).
// Scoreboard: R8 all-arch+spill~150 = 318us (best). R11 pins but arch
//   156>128 = 431us. R14/R15 1-wave/SIMD = 528/425us. R13 unroll-2 =
//   2107us (runtime-idx -> all-scratch; NEVER partial-unroll).
// R16 (this round): the one untested cell = 8-wave TLP + both halves fit:
//   AGPR(pinned) = wi1 64 + wh1 64 = 128 exactly (R11-proven pin pair).
//   arch = wh0 64 + acc <=24 + B-frags ~8-16 + misc ~10 + transient bias
//   temps ~8 ~= 106-122 <= 128 (bias/wi0 live in LDS, R13-proven; zero
//   C-in accs, bias added at tanh -- identical f32 math).
// Floor: 128 wave-ds_read_b128/step ~1540cyc -> ~130-180us.
// FALSIFIABLE: WRITE_SIZE 8.85 -> <3MB, dur 150-250us.
// KILL-GATE: dur >= 318us => full-residency family exhausted.

#define Bsz 1024
#define Tt  187
#define Hh  256
#define Cc  5
#define ST  264      // f16 elems per batch-col row (256 + 8 pad)
#define XS  188      // x LDS stride (187 + 1)

typedef _Float16 f16x8 __attribute__((ext_vector_type(8)));
typedef __fp16   fp16x2 __attribute__((ext_vector_type(2)));  // cvt_pkrtz native type
typedef float    f32x4 __attribute__((ext_vector_type(4)));

// Force a fragment into the AGPR half of the unified file (R11/R15-proven).
#define PIN_AGPR(v) asm volatile("" : "+a"(v))

__device__ __forceinline__ float tanh_fast(float z) {
    float e = __expf(2.0f * z);
    return 1.0f - 2.0f * __builtin_amdgcn_rcpf(1.0f + e);
}

__device__ __forceinline__ unsigned pk2(float a, float b) {
    union { fp16x2 h; unsigned u; } v;
    v.h = __builtin_amdgcn_cvt_pkrtz(a, b);
    return v.u;
}

__global__ void __launch_bounds__(512, 2)
rnn_fused(const float* __restrict__ x,     // [B][T]
          const float* __restrict__ Wih0,  // [H][1]
          const float* __restrict__ Whh0,  // [H][H]
          const float* __restrict__ bih0,
          const float* __restrict__ bhh0,
          const float* __restrict__ Wih1,  // [H][H]
          const float* __restrict__ Whh1,  // [H][H]
          const float* __restrict__ bih1,
          const float* __restrict__ bhh1,
          const float* __restrict__ Wfc,   // [C][H]
          const float* __restrict__ bfc,   // [C]
          float* __restrict__ out)         // [B][C]
{
    __shared__ __align__(16) _Float16 ht0[2][16 * ST];
    __shared__ __align__(16) _Float16 ht1[2][16 * ST];
    __shared__ float xs[16 * XS];
    __shared__ __align__(16) float bias_lds[3 * Hh];  // [0]=b0sum [1]=b1sum [2]=wi0

    const int tid  = threadIdx.x;
    const int lane = tid & 63;
    const int w    = tid >> 6;     // wave 0..7 -> features [32w, 32w+32)
    const int q    = lane >> 4;
    const int c    = lane & 15;    // batch col within block
    const int bb   = blockIdx.x * 16;

    // ---- one-time: stage weight A-fragments (f16) ----
    // A-layout: lane (q,c) reg j holds A[m=fb+c][k=kt*32+q*8+j].
    // wi1, wh1 -> AGPR half (pinned, 128 exactly). wh0 -> arch VGPRs (64).
    f16x8 wh0[2][8], wi1[2][8], wh1[2][8];
#pragma unroll
    for (int mt = 0; mt < 2; ++mt) {
        const int fb = 32 * w + 16 * mt;
        const int m = fb + c;
#pragma unroll
        for (int kt = 0; kt < 8; ++kt) {
            const int off = m * Hh + kt * 32 + q * 8;
            {
                const float4 a0 = *(const float4*)(Whh0 + off);
                const float4 a1 = *(const float4*)(Whh0 + off + 4);
                wh0[mt][kt] = (f16x8){(_Float16)a0.x, (_Float16)a0.y, (_Float16)a0.z, (_Float16)a0.w,
                                      (_Float16)a1.x, (_Float16)a1.y, (_Float16)a1.z, (_Float16)a1.w};
            }
            {
                const float4 a0 = *(const float4*)(Wih1 + off);
                const float4 a1 = *(const float4*)(Wih1 + off + 4);
                wi1[mt][kt] = (f16x8){(_Float16)a0.x, (_Float16)a0.y, (_Float16)a0.z, (_Float16)a0.w,
                                      (_Float16)a1.x, (_Float16)a1.y, (_Float16)a1.z, (_Float16)a1.w};
                PIN_AGPR(wi1[mt][kt]);
            }
            {
                const float4 a0 = *(const float4*)(Whh1 + off);
                const float4 a1 = *(const float4*)(Whh1 + off + 4);
                wh1[mt][kt] = (f16x8){(_Float16)a0.x, (_Float16)a0.y, (_Float16)a0.z, (_Float16)a0.w,
                                      (_Float16)a1.x, (_Float16)a1.y, (_Float16)a1.z, (_Float16)a1.w};
                PIN_AGPR(wh1[mt][kt]);
            }
        }
    }

    // ---- init LDS: x tile, biases, ht1 = 0 (both buffers), ht0[0] ----
    for (int i = tid; i < 16 * Tt; i += 512) {
        const int b = i / Tt, t = i - b * Tt;
        xs[b * XS + t] = x[(bb + b) * Tt + t];
    }
    if (tid < Hh) {
        bias_lds[tid]           = bih0[tid] + bhh0[tid];
        bias_lds[Hh + tid]      = bih1[tid] + bhh1[tid];
        bias_lds[2 * Hh + tid]  = Wih0[tid];
    }
    {
        _Float16* z = &ht1[0][0];
        for (int i = tid; i < 2 * 16 * ST; i += 512) z[i] = (_Float16)0.f;
    }
    for (int i = tid; i < 16 * Hh; i += 512) {
        const int b = i >> 8, f = i & 255;
        const float xv0 = x[(bb + b) * Tt];
        ht0[0][b * ST + f] =
            (_Float16)tanh_fast(xv0 * Wih0[f] + bih0[f] + bhh0[f]);
    }
    __syncthreads();

    // B-operand read base: lane (q,c) reg j needs ht[k=kt*32+q*8+j][col c]
    const int rdoff = c * ST + q * 8;
    const int wroff = c * ST + 32 * w + 4 * q;   // D write: [c][fb+4q .. +3]
    const int fq    = 32 * w + 4 * q;            // bias base for mt=0 (+16 for mt=1)

    // ---- main recurrence, time-skewed:
    // step s: B0 = ht0[s]; produce ht0[s+1] (Whh0) and ht1[s] (Wih1 + Whh1)
#pragma unroll 1
    for (int s = 0; s < Tt; ++s) {
        const int cur = s & 1, nxt = cur ^ 1;
        const _Float16* B0p = &ht0[cur][rdoff];
        const _Float16* B1p = &ht1[nxt][rdoff];   // ht1[s-1]
        int sn = s + 1; if (sn >= Tt) sn = Tt - 1;  // last h0_next unused
        const float xv = xs[c * XS + sn];

        // layer0: ai = Wih1 . ht0 ; ah0 = Whh0 . ht0 (shared B-frag).
        // Zero C-in; biases added at tanh (identical f32 adds).
        const f32x4 z4 = (f32x4){0.f, 0.f, 0.f, 0.f};
        f32x4 ai[2]  = {z4, z4};
        f32x4 ah0[2] = {z4, z4};
#pragma unroll
        for (int kt = 0; kt < 8; ++kt) {
            const f16x8 B = *(const f16x8*)(B0p + kt * 32);
            ai[0]  = __builtin_amdgcn_mfma_f32_16x16x32_f16(wi1[0][kt], B, ai[0],  0, 0, 0);
            ai[1]  = __builtin_amdgcn_mfma_f32_16x16x32_f16(wi1[1][kt], B, ai[1],  0, 0, 0);
            ah0[0] = __builtin_amdgcn_mfma_f32_16x16x32_f16(wh0[0][kt], B, ah0[0], 0, 0, 0);
            ah0[1] = __builtin_amdgcn_mfma_f32_16x16x32_f16(wh0[1][kt], B, ah0[1], 0, 0, 0);
        }
        // ht0[s+1] = tanh(ah0 + b0 + x_{s+1} * wi0), pack f16, 8B LDS writes
#pragma unroll
        for (int mt = 0; mt < 2; ++mt) {
            const float4 b0r = *(const float4*)&bias_lds[fq + 16 * mt];
            const float4 w0r = *(const float4*)&bias_lds[2 * Hh + fq + 16 * mt];
            const float t0 = tanh_fast(ah0[mt][0] + b0r.x + xv * w0r.x);
            const float t1 = tanh_fast(ah0[mt][1] + b0r.y + xv * w0r.y);
            const float t2 = tanh_fast(ah0[mt][2] + b0r.z + xv * w0r.z);
            const float t3 = tanh_fast(ah0[mt][3] + b0r.w + xv * w0r.w);
            *(uint2*)(&ht0[nxt][wroff + 16 * mt]) = make_uint2(pk2(t0, t1), pk2(t2, t3));
        }

        // layer1: ah1 = Whh1 . ht1[s-1]; weights AGPR-resident
        f32x4 ah1[2] = {z4, z4};
#pragma unroll
        for (int kt = 0; kt < 8; ++kt) {
            const f16x8 B = *(const f16x8*)(B1p + kt * 32);
            ah1[0] = __builtin_amdgcn_mfma_f32_16x16x32_f16(wh1[0][kt], B, ah1[0], 0, 0, 0);
            ah1[1] = __builtin_amdgcn_mfma_f32_16x16x32_f16(wh1[1][kt], B, ah1[1], 0, 0, 0);
        }
        // ht1[s] = tanh(ai + ah1 + b1)
#pragma unroll
        for (int mt = 0; mt < 2; ++mt) {
            const float4 b1r = *(const float4*)&bias_lds[Hh + fq + 16 * mt];
            const float t0 = tanh_fast(ai[mt][0] + ah1[mt][0] + b1r.x);
            const float t1 = tanh_fast(ai[mt][1] + ah1[mt][1] + b1r.y);
            const float t2 = tanh_fast(ai[mt][2] + ah1[mt][2] + b1r.z);
            const float t3 = tanh_fast(ai[mt][3] + ah1[mt][3] + b1r.w);
            *(uint2*)(&ht1[cur][wroff + 16 * mt]) = make_uint2(pk2(t0, t1), pk2(t2, t3));
        }
        __syncthreads();   // double-buffered: one barrier per step
    }

    // ---- FC epilogue: out[bb+b][cls] = ht1_final[.][b] . Wfc[cls] + bfc ----
    if (tid < 16 * Cc) {
        const int b = tid / Cc, cls = tid - Cc * (tid / Cc);
        const _Float16* h = &ht1[(Tt - 1) & 1][b * ST];
        float acc = bfc[cls];
        for (int k = 0; k < Hh; ++k)
            acc += (float)h[k] * Wfc[cls * Hh + k];
        out[(bb + b) * Cc + cls] = acc;
    }
}

extern "C" void kernel_launch(void* const* d_in, const int* in_sizes, int n_in,
                              void* d_out, int out_size, void* d_ws, size_t ws_size,
                              hipStream_t stream) {
    rnn_fused<<<dim3(Bsz / 16), dim3(512), 0, stream>>>(
        (const float*)d_in[0],  // x
        (const float*)d_in[1],  // W_ih0
        (const float*)d_in[2],  // W_hh0
        (const float*)d_in[3],  // b_ih0
        (const float*)d_in[4],  // b_hh0
        (const float*)d_in[5],  // W_ih1
        (const float*)d_in[6],  // W_hh1
        (const float*)d_in[7],  // b_ih1
        (const float*)d_in[8],  // b_hh1
        (const float*)d_in[9],  // W_fc
        (const float*)d_in[10], // b_fc
        (float*)d_out);
}